// Round 1
// baseline (734.212 us; speedup 1.0000x reference)
//
#include <hip/hip_runtime.h>
#include <math.h>

#define DIM 1024
#define NH 16
#define NKV 4
#define HD 64
#define WINDOW 16

// ---------------- generic fp32 GEMM: C[M,N] = A[M,K] @ B[N,K]^T ----------------
#define BM 64
#define BN 64
#define BK 16

__global__ __launch_bounds__(256) void gemm_nt(const float* __restrict__ A,
                                               const float* __restrict__ B,
                                               float* __restrict__ C,
                                               int M, int N, int K) {
  __shared__ float As[BK][BM + 1];
  __shared__ float Bs[BK][BN + 1];
  const int tx = threadIdx.x & 15;
  const int ty = threadIdx.x >> 4;
  const int row0 = blockIdx.y * BM;
  const int col0 = blockIdx.x * BN;
  float acc[4][4] = {};
  for (int k0 = 0; k0 < K; k0 += BK) {
#pragma unroll
    for (int i = 0; i < 4; i++) {
      int idx = threadIdx.x + i * 256;   // 0..1023 covers 64x16 tile
      int r = idx >> 4, c = idx & 15;
      As[c][r] = A[(size_t)(row0 + r) * K + k0 + c];
      Bs[c][r] = B[(size_t)(col0 + r) * K + k0 + c];
    }
    __syncthreads();
#pragma unroll
    for (int kk = 0; kk < BK; kk++) {
      float a[4], b[4];
#pragma unroll
      for (int i = 0; i < 4; i++) a[i] = As[kk][ty * 4 + i];
#pragma unroll
      for (int j = 0; j < 4; j++) b[j] = Bs[kk][tx * 4 + j];
#pragma unroll
      for (int i = 0; i < 4; i++)
#pragma unroll
        for (int j = 0; j < 4; j++) acc[i][j] += a[i] * b[j];
    }
    __syncthreads();
  }
#pragma unroll
  for (int i = 0; i < 4; i++)
#pragma unroll
    for (int j = 0; j < 4; j++)
      C[(size_t)(row0 + ty * 4 + i) * N + col0 + tx * 4 + j] = acc[i][j];
}

// ---------------- per-head RMSNorm (in place), one wave per 64-dim vector ------
__global__ __launch_bounds__(256) void rmsnorm_heads(float* __restrict__ x,
                                                     const float* __restrict__ w,
                                                     int nvec) {
  int gid = blockIdx.x * blockDim.x + threadIdx.x;
  int vec = gid >> 6;
  int lane = gid & 63;
  if (vec >= nvec) return;
  float val = x[(size_t)vec * 64 + lane];
  float ss = val * val;
#pragma unroll
  for (int off = 32; off >= 1; off >>= 1) ss += __shfl_xor(ss, off);
  float norm = rsqrtf(ss * (1.0f / 64.0f) + 0.01f);
  x[(size_t)vec * 64 + lane] = val * norm * w[lane];
}

// ---------------- banded ALiBi attention: one wave per (b*L+i, h) -------------
// q: [B*L, NH*HD], k/v: [B*L, NKV*HD], o: [B*L, NH*HD]
__global__ __launch_bounds__(256) void attn_kernel(const float* __restrict__ q,
                                                   const float* __restrict__ k,
                                                   const float* __restrict__ v,
                                                   float* __restrict__ o,
                                                   int L) {
  int gid = blockIdx.x * blockDim.x + threadIdx.x;
  int wave = gid >> 6;
  int lane = gid & 63;
  int h = wave & (NH - 1);
  int row = wave >> 4;        // b*L + i
  int i = row & (L - 1);      // L is a power of two (2048)
  int rowbase = row - i;      // b*L
  int kvh = h & (NKV - 1);    // GQA: kv head = h % NKV (torch expand order)

  const float slope = exp2f(-0.5f * (float)(h + 1));  // closest=16 -> base=2^-0.5
  const float scale = 0.125f;                          // 1/sqrt(64)

  float ql = q[(size_t)row * (NH * HD) + h * HD + lane];

  float scores[WINDOW + 1];
#pragma unroll
  for (int jj = 0; jj <= WINDOW; jj++) {
    int j = i - WINDOW + jj;
    float s = -INFINITY;
    if (j >= 0) {
      float kl = k[(size_t)(rowbase + j) * (NKV * HD) + kvh * HD + lane];
      float d = ql * kl;
#pragma unroll
      for (int off = 32; off >= 1; off >>= 1) d += __shfl_xor(d, off);
      s = d * scale + slope * (float)(j - i);
    }
    scores[jj] = s;
  }

  float m = scores[WINDOW];   // j == i always in-window
#pragma unroll
  for (int jj = 0; jj < WINDOW; jj++) m = fmaxf(m, scores[jj]);

  float sum = 0.0f, acc = 0.0f;
#pragma unroll
  for (int jj = 0; jj <= WINDOW; jj++) {
    int j = i - WINDOW + jj;
    float p = __expf(scores[jj] - m);   // exp(-inf) == 0 for masked lanes
    sum += p;
    if (j >= 0) {
      acc += p * v[(size_t)(rowbase + j) * (NKV * HD) + kvh * HD + lane];
    }
  }
  o[(size_t)row * (NH * HD) + h * HD + lane] = acc / sum;
}

extern "C" void kernel_launch(void* const* d_in, const int* in_sizes, int n_in,
                              void* d_out, int out_size, void* d_ws, size_t ws_size,
                              hipStream_t stream) {
  const float* x  = (const float*)d_in[0];
  const float* wq = (const float*)d_in[1];
  const float* wk = (const float*)d_in[2];
  const float* wv = (const float*)d_in[3];
  const float* wo = (const float*)d_in[4];
  const float* qw = (const float*)d_in[5];
  const float* kw = (const float*)d_in[6];
  float* out = (float*)d_out;

  const int B = 2, L = 2048;
  const int M = B * L;  // 4096 token rows

  // workspace layout (floats): q | k | v | y  => 4096*(1024+256+256+1024)*4 B ~= 42 MB
  float* q    = (float*)d_ws;
  float* kbuf = q    + (size_t)M * (NH * HD);
  float* vbuf = kbuf + (size_t)M * (NKV * HD);
  float* y    = vbuf + (size_t)M * (NKV * HD);

  dim3 blk(256);
  // projections
  gemm_nt<<<dim3(DIM / BN, M / BM), blk, 0, stream>>>(x, wq, q,    M, NH * HD,  DIM);
  gemm_nt<<<dim3((NKV * HD) / BN, M / BM), blk, 0, stream>>>(x, wk, kbuf, M, NKV * HD, DIM);
  gemm_nt<<<dim3((NKV * HD) / BN, M / BM), blk, 0, stream>>>(x, wv, vbuf, M, NKV * HD, DIM);
  // per-head rmsnorm on q, k
  rmsnorm_heads<<<(M * NH) / 4,  blk, 0, stream>>>(q,    qw, M * NH);
  rmsnorm_heads<<<(M * NKV) / 4, blk, 0, stream>>>(kbuf, kw, M * NKV);
  // banded attention
  attn_kernel<<<(M * NH) / 4, blk, 0, stream>>>(q, kbuf, vbuf, y, L);
  // output projection
  gemm_nt<<<dim3(DIM / BN, M / BM), blk, 0, stream>>>(y, wo, out, M, DIM, DIM);
}

// Round 2
// 266.942 us; speedup vs baseline: 2.7505x; 2.7505x over previous
//
#include <hip/hip_runtime.h>
#include <math.h>

#define DIM 1024
#define NH 16
#define NKV 4
#define HD 64
#define WINDOW 16

typedef __bf16 bf16_t;
typedef bf16_t bf16x8 __attribute__((ext_vector_type(8)));
typedef bf16_t bf16x4 __attribute__((ext_vector_type(4)));
typedef float f32x4 __attribute__((ext_vector_type(4)));

// ---------------- fp32 -> bf16 conversion, 4 elems/thread ----------------
__global__ __launch_bounds__(256) void f2bf(const float* __restrict__ in,
                                            bf16_t* __restrict__ out, int n4) {
  int i = blockIdx.x * blockDim.x + threadIdx.x;
  if (i >= n4) return;
  float4 f = ((const float4*)in)[i];
  bf16x4 o = {(bf16_t)f.x, (bf16_t)f.y, (bf16_t)f.z, (bf16_t)f.w};
  ((bf16x4*)out)[i] = o;
}

// ---------------- bf16 MFMA GEMM (m97 structure): C[M,N] = A[M,K] @ B[N,K]^T
// 128x128 tile, BK=32, 4 waves (2x2), each wave 64x64 via 4x4 of 16x16x32 MFMA.
template <typename CT>
__global__ __launch_bounds__(256) void gemm_bf16(const bf16_t* __restrict__ A,
                                                 const bf16_t* __restrict__ B,
                                                 CT* __restrict__ C,
                                                 int M, int N, int K) {
  __shared__ bf16_t As[128 * 32];
  __shared__ bf16_t Bs[128 * 32];
  const int t = threadIdx.x;
  const int lane = t & 63;
  const int wid = t >> 6;
  const int row0 = blockIdx.y * 128;
  const int col0 = blockIdx.x * 128;
  const int wm = (wid >> 1) * 64;
  const int wn = (wid & 1) * 64;
  const int lquad = lane >> 4;   // k-chunk for fragments; row-group for C
  const int lcol = lane & 15;

  f32x4 acc[4][4] = {};

  for (int k0 = 0; k0 < K; k0 += 32) {
    const bf16_t* Ag = A + (size_t)row0 * K + k0;
    const bf16_t* Bg = B + (size_t)col0 * K + k0;
#pragma unroll
    for (int i = 0; i < 2; i++) {
      int c = t + i * 256;           // chunk id 0..511, 16B each
      int r = c >> 2, cc = c & 3;    // tile row, 16B col-chunk
      __builtin_amdgcn_global_load_lds(
          (const __attribute__((address_space(1))) void*)(Ag + (size_t)r * K + cc * 8),
          (__attribute__((address_space(3))) void*)(As + c * 8), 16, 0, 0);
      __builtin_amdgcn_global_load_lds(
          (const __attribute__((address_space(1))) void*)(Bg + (size_t)r * K + cc * 8),
          (__attribute__((address_space(3))) void*)(Bs + c * 8), 16, 0, 0);
    }
    __syncthreads();

    bf16x8 af[4], bfr[4];
#pragma unroll
    for (int mi = 0; mi < 4; mi++)
      af[mi] = *(const bf16x8*)(As + (wm + mi * 16 + lcol) * 32 + lquad * 8);
#pragma unroll
    for (int ni = 0; ni < 4; ni++)
      bfr[ni] = *(const bf16x8*)(Bs + (wn + ni * 16 + lcol) * 32 + lquad * 8);
#pragma unroll
    for (int mi = 0; mi < 4; mi++)
#pragma unroll
      for (int ni = 0; ni < 4; ni++)
        acc[mi][ni] = __builtin_amdgcn_mfma_f32_16x16x32_bf16(af[mi], bfr[ni],
                                                              acc[mi][ni], 0, 0, 0);
    __syncthreads();
  }

  // C/D layout (m89-verified): col = lane&15, row = (lane>>4)*4 + r
#pragma unroll
  for (int mi = 0; mi < 4; mi++)
#pragma unroll
    for (int ni = 0; ni < 4; ni++) {
      size_t base = (size_t)(row0 + wm + mi * 16 + lquad * 4) * N + col0 + wn + ni * 16 + lcol;
#pragma unroll
      for (int r = 0; r < 4; r++)
        C[base + (size_t)r * N] = (CT)acc[mi][ni][r];
    }
}

// ---------------- per-head RMSNorm in place on bf16 qkv [4096, 1536] ----------
// vectors: 65536 q vectors (heads 0..15), then 16384 k vectors (heads 0..3)
__global__ __launch_bounds__(256) void rmsnorm_qk(bf16_t* __restrict__ qkv,
                                                  const float* __restrict__ qw,
                                                  const float* __restrict__ kw) {
  int gid = blockIdx.x * blockDim.x + threadIdx.x;
  int vec = gid >> 6;
  int lane = gid & 63;
  bf16_t* p;
  const float* w;
  if (vec < 65536) {
    int r = vec >> 4, h = vec & 15;
    p = qkv + (size_t)r * 1536 + h * 64;
    w = qw;
  } else {
    int v2 = vec - 65536;
    int r = v2 >> 2, h = v2 & 3;
    p = qkv + (size_t)r * 1536 + 1024 + h * 64;
    w = kw;
  }
  float val = (float)p[lane];
  float ss = val * val;
#pragma unroll
  for (int off = 32; off >= 1; off >>= 1) ss += __shfl_xor(ss, off);
  float norm = rsqrtf(ss * (1.0f / 64.0f) + 0.01f);
  p[lane] = (bf16_t)(val * norm * w[lane]);
}

// ---------------- banded ALiBi attention: one wave per (b*L+i, h) -------------
// qkv: [4096, 1536] bf16 (q | k | v), y: [4096, 1024] bf16
__global__ __launch_bounds__(256) void attn_kernel(const bf16_t* __restrict__ qkv,
                                                   bf16_t* __restrict__ y, int L) {
  int gid = blockIdx.x * blockDim.x + threadIdx.x;
  int wave = gid >> 6;
  int lane = gid & 63;
  int h = wave & (NH - 1);
  int row = wave >> 4;        // b*L + i
  int i = row & (L - 1);      // L = 2048 (pow2)
  int rowbase = row - i;      // b*L
  int kvh = h & (NKV - 1);    // GQA: kv head = h % NKV

  const float slope = exp2f(-0.5f * (float)(h + 1));
  const float scale = 0.125f;

  float ql = (float)qkv[(size_t)row * 1536 + h * 64 + lane];

  float scores[WINDOW + 1];
#pragma unroll
  for (int jj = 0; jj <= WINDOW; jj++) {
    int j = i - WINDOW + jj;
    float s = -INFINITY;
    if (j >= 0) {
      float kl = (float)qkv[(size_t)(rowbase + j) * 1536 + 1024 + kvh * 64 + lane];
      float d = ql * kl;
#pragma unroll
      for (int off = 32; off >= 1; off >>= 1) d += __shfl_xor(d, off);
      s = d * scale + slope * (float)(j - i);
    }
    scores[jj] = s;
  }

  float m = scores[WINDOW];
#pragma unroll
  for (int jj = 0; jj < WINDOW; jj++) m = fmaxf(m, scores[jj]);

  float sum = 0.0f, acc = 0.0f;
#pragma unroll
  for (int jj = 0; jj <= WINDOW; jj++) {
    int j = i - WINDOW + jj;
    float p = __expf(scores[jj] - m);
    sum += p;
    if (j >= 0) {
      acc += p * (float)qkv[(size_t)(rowbase + j) * 1536 + 1280 + kvh * 64 + lane];
    }
  }
  y[(size_t)row * 1024 + h * 64 + lane] = (bf16_t)(acc / sum);
}

extern "C" void kernel_launch(void* const* d_in, const int* in_sizes, int n_in,
                              void* d_out, int out_size, void* d_ws, size_t ws_size,
                              hipStream_t stream) {
  const float* x  = (const float*)d_in[0];
  const float* wq = (const float*)d_in[1];
  const float* wk = (const float*)d_in[2];
  const float* wv = (const float*)d_in[3];
  const float* wo = (const float*)d_in[4];
  const float* qw = (const float*)d_in[5];
  const float* kw = (const float*)d_in[6];
  float* out = (float*)d_out;

  const int M = 4096;   // B*L
  const int L = 2048;

  // workspace (bf16 elems): xb | wqkvb | wob | qkv | yb  (~33 MB)
  bf16_t* xb    = (bf16_t*)d_ws;
  bf16_t* wqkvb = xb + (size_t)M * DIM;                    // [1536, 1024]
  bf16_t* wob   = wqkvb + (size_t)1536 * DIM;              // [1024, 1024]
  bf16_t* qkv   = wob + (size_t)DIM * DIM;                 // [4096, 1536]
  bf16_t* yb    = qkv + (size_t)M * 1536;                  // [4096, 1024]

  dim3 blk(256);
  // conversions
  f2bf<<<(M * DIM / 4) / 256, blk, 0, stream>>>(x, xb, M * DIM / 4);
  f2bf<<<(1024 * DIM / 4) / 256, blk, 0, stream>>>(wq, wqkvb, 1024 * DIM / 4);
  f2bf<<<(256 * DIM / 4) / 256, blk, 0, stream>>>(wk, wqkvb + (size_t)1024 * DIM, 256 * DIM / 4);
  f2bf<<<(256 * DIM / 4) / 256, blk, 0, stream>>>(wv, wqkvb + (size_t)1280 * DIM, 256 * DIM / 4);
  f2bf<<<(DIM * DIM / 4) / 256, blk, 0, stream>>>(wo, wob, DIM * DIM / 4);

  // fused QKV projection: qkv[4096,1536] = xb @ wqkvb^T  (bf16 out)
  gemm_bf16<bf16_t><<<dim3(1536 / 128, M / 128), blk, 0, stream>>>(xb, wqkvb, qkv, M, 1536, DIM);

  // per-head rmsnorm on q,k (in place)
  rmsnorm_qk<<<(81920 * 64) / 256, blk, 0, stream>>>(qkv, qw, kw);

  // banded attention -> yb [4096,1024] bf16
  attn_kernel<<<(M * NH) / 4, blk, 0, stream>>>(qkv, yb, L);

  // output projection: out[4096,1024] = yb @ wob^T  (fp32 out)
  gemm_bf16<float><<<dim3(DIM / 128, M / 128), blk, 0, stream>>>(yb, wob, out, M, DIM, DIM);
}

// Round 3
// 163.962 us; speedup vs baseline: 4.4779x; 1.6281x over previous
//
#include <hip/hip_runtime.h>
#include <math.h>

#define DIM 1024
#define NH 16
#define NKV 4
#define HD 64
#define WINDOW 16

typedef __bf16 bf16_t;
typedef bf16_t bf16x8 __attribute__((ext_vector_type(8)));
typedef bf16_t bf16x4 __attribute__((ext_vector_type(4)));
typedef float f32x4 __attribute__((ext_vector_type(4)));

// ---------------- fused fp32 -> bf16 conversion of all 5 tensors ----------------
// segments (vec4 counts): x 1048576 | wq 262144 | wk 65536 | wv 65536 | wo 262144
__global__ __launch_bounds__(256) void f2bf_all(const float* __restrict__ x,
                                                const float* __restrict__ wq,
                                                const float* __restrict__ wk,
                                                const float* __restrict__ wv,
                                                const float* __restrict__ wo,
                                                bf16_t* __restrict__ xb,
                                                bf16_t* __restrict__ wqkvb,
                                                bf16_t* __restrict__ wob) {
  int i = blockIdx.x * blockDim.x + threadIdx.x;
  const float* src;
  bf16_t* dst;
  int off;
  if (i < 1048576) { src = x; dst = xb; off = i; }
  else if (i < 1310720) { src = wq; dst = wqkvb; off = i - 1048576; }
  else if (i < 1376256) { src = wk; dst = wqkvb + (size_t)1024 * DIM / 4 * 4; off = i - 1310720; }
  else if (i < 1441792) { src = wv; dst = wqkvb + (size_t)1280 * DIM; off = i - 1376256; }
  else { src = wo; dst = wob; off = i - 1441792; }
  float4 f = ((const float4*)src)[off];
  bf16x4 o = {(bf16_t)f.x, (bf16_t)f.y, (bf16_t)f.z, (bf16_t)f.w};
  ((bf16x4*)dst)[off] = o;
}

// ---------------- bf16 MFMA GEMM (m97 structure): C[M,N] = A[M,K] @ B[N,K]^T
template <typename CT>
__global__ __launch_bounds__(256) void gemm_bf16(const bf16_t* __restrict__ A,
                                                 const bf16_t* __restrict__ B,
                                                 CT* __restrict__ C,
                                                 int M, int N, int K) {
  __shared__ bf16_t As[128 * 32];
  __shared__ bf16_t Bs[128 * 32];
  const int t = threadIdx.x;
  const int lane = t & 63;
  const int wid = t >> 6;
  const int row0 = blockIdx.y * 128;
  const int col0 = blockIdx.x * 128;
  const int wm = (wid >> 1) * 64;
  const int wn = (wid & 1) * 64;
  const int lquad = lane >> 4;
  const int lcol = lane & 15;

  f32x4 acc[4][4] = {};

  for (int k0 = 0; k0 < K; k0 += 32) {
    const bf16_t* Ag = A + (size_t)row0 * K + k0;
    const bf16_t* Bg = B + (size_t)col0 * K + k0;
#pragma unroll
    for (int i = 0; i < 2; i++) {
      int c = t + i * 256;
      int r = c >> 2, cc = c & 3;
      __builtin_amdgcn_global_load_lds(
          (const __attribute__((address_space(1))) void*)(Ag + (size_t)r * K + cc * 8),
          (__attribute__((address_space(3))) void*)(As + c * 8), 16, 0, 0);
      __builtin_amdgcn_global_load_lds(
          (const __attribute__((address_space(1))) void*)(Bg + (size_t)r * K + cc * 8),
          (__attribute__((address_space(3))) void*)(Bs + c * 8), 16, 0, 0);
    }
    __syncthreads();

    bf16x8 af[4], bfr[4];
#pragma unroll
    for (int mi = 0; mi < 4; mi++)
      af[mi] = *(const bf16x8*)(As + (wm + mi * 16 + lcol) * 32 + lquad * 8);
#pragma unroll
    for (int ni = 0; ni < 4; ni++)
      bfr[ni] = *(const bf16x8*)(Bs + (wn + ni * 16 + lcol) * 32 + lquad * 8);
#pragma unroll
    for (int mi = 0; mi < 4; mi++)
#pragma unroll
      for (int ni = 0; ni < 4; ni++)
        acc[mi][ni] = __builtin_amdgcn_mfma_f32_16x16x32_bf16(af[mi], bfr[ni],
                                                              acc[mi][ni], 0, 0, 0);
    __syncthreads();
  }

#pragma unroll
  for (int mi = 0; mi < 4; mi++)
#pragma unroll
    for (int ni = 0; ni < 4; ni++) {
      size_t base = (size_t)(row0 + wm + mi * 16 + lquad * 4) * N + col0 + wn + ni * 16 + lcol;
#pragma unroll
      for (int r = 0; r < 4; r++)
        C[base + (size_t)r * N] = (CT)acc[mi][ni][r];
    }
}

// ---------------- per-head RMSNorm in place on bf16 qkv [4096, 1536] ----------
__global__ __launch_bounds__(256) void rmsnorm_qk(bf16_t* __restrict__ qkv,
                                                  const float* __restrict__ qw,
                                                  const float* __restrict__ kw) {
  int gid = blockIdx.x * blockDim.x + threadIdx.x;
  int vec = gid >> 6;
  int lane = gid & 63;
  bf16_t* p;
  const float* w;
  if (vec < 65536) {
    int r = vec >> 4, h = vec & 15;
    p = qkv + (size_t)r * 1536 + h * 64;
    w = qw;
  } else {
    int v2 = vec - 65536;
    int r = v2 >> 2, h = v2 & 3;
    p = qkv + (size_t)r * 1536 + 1024 + h * 64;
    w = kw;
  }
  float val = (float)p[lane];
  float ss = val * val;
#pragma unroll
  for (int off = 32; off >= 1; off >>= 1) ss += __shfl_xor(ss, off);
  float norm = rsqrtf(ss * (1.0f / 64.0f) + 0.01f);
  p[lane] = (bf16_t)(val * norm * w[lane]);
}

// ---------------- MFMA banded ALiBi attention -------------------------------
// Block = 4 waves; block handles q-tile of 16 rows, heads hgroup*4 + w (w=0..3).
// Wave w's kv head = (hgroup*4+w) & 3 = w.
// qkv: [4096, 1536] bf16 (q | k | v), y: [4096, 1024] bf16
#define LKP 72  // K row stride in LDS (64 + 8 pad -> 144 B)
#define LVP 40  // VT / P row stride (32 + 8 pad -> 80 B)

__global__ __launch_bounds__(256) void attn_mfma(const bf16_t* __restrict__ qkv,
                                                 bf16_t* __restrict__ y) {
  __shared__ bf16_t Ks[4][32][LKP];   // [kvh][key][dim]
  __shared__ bf16_t VTs[4][64][LVP];  // [kvh][dim][key]
  __shared__ bf16_t Ps[4][16][LVP];   // [wave][qrow][key]

  const int t = threadIdx.x;
  const int lane = t & 63;
  const int w = t >> 6;
  const int tile = blockIdx.x >> 2;
  const int hgroup = blockIdx.x & 3;
  const int b = tile >> 7;               // batch (128 tiles per batch)
  const int i0loc = (tile & 127) << 4;   // local start row in batch
  const int rowbase = b << 11;           // global row of batch start
  const int rowg0 = rowbase + i0loc;     // global row of q-tile start

  // ---- stage K band: 4 kvh x 32 keys x 64 dims (16B per thread x 4 iters)
#pragma unroll
  for (int it = 0; it < 4; it++) {
    int chunk = t + it * 256;            // 0..1023
    int kvh = chunk >> 8;
    int key = (chunk >> 3) & 31;
    int dc = chunk & 7;
    int jloc = i0loc - 16 + key;
    int rg = rowbase + (jloc < 0 ? 0 : jloc);
    bf16x8 val = *(const bf16x8*)(qkv + (size_t)rg * 1536 + 1024 + kvh * 64 + dc * 8);
    *(bf16x8*)(&Ks[kvh][key][dc * 8]) = val;
  }
  // ---- stage V transposed: scalar (coalesced read, transposed write)
#pragma unroll
  for (int it = 0; it < 32; it++) {
    int idx = t + it * 256;              // 0..8191
    int dim = idx & 63;
    int key = (idx >> 6) & 31;
    int kvh = idx >> 11;
    int jloc = i0loc - 16 + key;
    int rg = rowbase + (jloc < 0 ? 0 : jloc);
    VTs[kvh][dim][key] = qkv[(size_t)rg * 1536 + 1280 + kvh * 64 + dim];
  }
  __syncthreads();

  const int col = lane & 15;
  const int quad = lane >> 4;
  const int h = hgroup * 4 + w;
  const int kvh = w;
  const float slope = exp2f(-0.5f * (float)(h + 1));

  // K fragments (B-operand): n = key (col), k = dim (quad*8 + e)
  bf16x8 kf[2][2];
#pragma unroll
  for (int kt = 0; kt < 2; kt++)
#pragma unroll
    for (int kc = 0; kc < 2; kc++)
      kf[kt][kc] = *(const bf16x8*)(&Ks[kvh][kt * 16 + col][kc * 32 + quad * 8]);
  // V fragments (B-operand): n = dim (nt*16+col), k = key (quad*8 + e)
  bf16x8 vf[4];
#pragma unroll
  for (int nt = 0; nt < 4; nt++)
    vf[nt] = *(const bf16x8*)(&VTs[kvh][nt * 16 + col][quad * 8]);

  // Q fragments (A-operand) straight from global: m = qrow (col), k = dim
  const bf16_t* qrow = qkv + (size_t)(rowg0 + col) * 1536 + h * 64;
  bf16x8 qf0 = *(const bf16x8*)(qrow + quad * 8);
  bf16x8 qf1 = *(const bf16x8*)(qrow + 32 + quad * 8);

  // QK^T: S[16 q x 32 keys] in two C-layout accumulators
  f32x4 s0 = {}, s1 = {};
  s0 = __builtin_amdgcn_mfma_f32_16x16x32_bf16(qf0, kf[0][0], s0, 0, 0, 0);
  s0 = __builtin_amdgcn_mfma_f32_16x16x32_bf16(qf1, kf[0][1], s0, 0, 0, 0);
  s1 = __builtin_amdgcn_mfma_f32_16x16x32_bf16(qf0, kf[1][0], s1, 0, 0, 0);
  s1 = __builtin_amdgcn_mfma_f32_16x16x32_bf16(qf1, kf[1][1], s1, 0, 0, 0);

  // scores + ALiBi + mask. C/D layout: col = lane&15 (key), row = quad*4+r (q)
  const bool t0dead = (i0loc == 0);  // key tile 0 entirely before batch start
  float sc0[4], sc1[4];
#pragma unroll
  for (int r = 0; r < 4; r++) {
    int rel0 = col - 16 - (quad * 4 + r);  // j - i for key tile 0
    int rel1 = rel0 + 16;                  // key tile 1
    bool m0 = t0dead || (rel0 < -WINDOW);  // rel0 <= -1 always (never > 0)
    bool m1 = (rel1 > 0);                  // rel1 >= -15 always
    sc0[r] = m0 ? -INFINITY : s0[r] * 0.125f + slope * (float)rel0;
    sc1[r] = m1 ? -INFINITY : s1[r] * 0.125f + slope * (float)rel1;
  }
  // row max / sum over the 16 lanes of each quad group
  float mx[4], sum[4], p0[4], p1[4];
#pragma unroll
  for (int r = 0; r < 4; r++) mx[r] = fmaxf(sc0[r], sc1[r]);
#pragma unroll
  for (int off = 8; off >= 1; off >>= 1)
#pragma unroll
    for (int r = 0; r < 4; r++) mx[r] = fmaxf(mx[r], __shfl_xor(mx[r], off));
#pragma unroll
  for (int r = 0; r < 4; r++) {
    p0[r] = __expf(sc0[r] - mx[r]);
    p1[r] = __expf(sc1[r] - mx[r]);
    sum[r] = p0[r] + p1[r];
  }
#pragma unroll
  for (int off = 8; off >= 1; off >>= 1)
#pragma unroll
    for (int r = 0; r < 4; r++) sum[r] += __shfl_xor(sum[r], off);

  // P -> LDS (C-layout write), reread as A-operand
#pragma unroll
  for (int r = 0; r < 4; r++) {
    Ps[w][quad * 4 + r][col] = (bf16_t)p0[r];
    Ps[w][quad * 4 + r][16 + col] = (bf16_t)p1[r];
  }
  __syncthreads();
  bf16x8 pf = *(const bf16x8*)(&Ps[w][col][quad * 8]);

  // PV: O[16 q x 64 dim] in 4 C-layout accumulators
  f32x4 o[4] = {};
#pragma unroll
  for (int nt = 0; nt < 4; nt++)
    o[nt] = __builtin_amdgcn_mfma_f32_16x16x32_bf16(pf, vf[nt], o[nt], 0, 0, 0);

  // store normalized output
#pragma unroll
  for (int nt = 0; nt < 4; nt++)
#pragma unroll
    for (int r = 0; r < 4; r++)
      y[(size_t)(rowg0 + quad * 4 + r) * 1024 + h * 64 + nt * 16 + col] =
          (bf16_t)(o[nt][r] / sum[r]);
}

extern "C" void kernel_launch(void* const* d_in, const int* in_sizes, int n_in,
                              void* d_out, int out_size, void* d_ws, size_t ws_size,
                              hipStream_t stream) {
  const float* x  = (const float*)d_in[0];
  const float* wq = (const float*)d_in[1];
  const float* wk = (const float*)d_in[2];
  const float* wv = (const float*)d_in[3];
  const float* wo = (const float*)d_in[4];
  const float* qw = (const float*)d_in[5];
  const float* kw = (const float*)d_in[6];
  float* out = (float*)d_out;

  const int M = 4096;  // B*L

  // workspace (bf16 elems): xb | wqkvb | wob | qkv | yb
  bf16_t* xb    = (bf16_t*)d_ws;
  bf16_t* wqkvb = xb + (size_t)M * DIM;        // [1536, 1024]
  bf16_t* wob   = wqkvb + (size_t)1536 * DIM;  // [1024, 1024]
  bf16_t* qkv   = wob + (size_t)DIM * DIM;     // [4096, 1536]
  bf16_t* yb    = qkv + (size_t)M * 1536;      // [4096, 1024]

  dim3 blk(256);
  // fused conversions: 1703936 vec4 elements
  f2bf_all<<<1703936 / 256, blk, 0, stream>>>(x, wq, wk, wv, wo, xb, wqkvb, wob);

  // fused QKV projection: qkv[4096,1536] = xb @ wqkvb^T (bf16 out)
  gemm_bf16<bf16_t><<<dim3(1536 / 128, M / 128), blk, 0, stream>>>(xb, wqkvb, qkv, M, 1536, DIM);

  // per-head rmsnorm on q,k (in place)
  rmsnorm_qk<<<(81920 * 64) / 256, blk, 0, stream>>>(qkv, qw, kw);

  // MFMA banded attention -> yb [4096,1024] bf16
  attn_mfma<<<1024, blk, 0, stream>>>(qkv, yb);

  // output projection: out[4096,1024] = yb @ wob^T (fp32 out)
  gemm_bf16<float><<<dim3(DIM / 128, M / 128), blk, 0, stream>>>(yb, wob, out, M, DIM, DIM);
}

// Round 4
// 154.764 us; speedup vs baseline: 4.7441x; 1.0594x over previous
//
#include <hip/hip_runtime.h>
#include <math.h>

#define DIM 1024
#define NH 16
#define NKV 4
#define HD 64
#define WINDOW 16
#define EPS 0.01f

typedef __bf16 bf16_t;
typedef bf16_t bf16x8 __attribute__((ext_vector_type(8)));
typedef bf16_t bf16x4 __attribute__((ext_vector_type(4)));
typedef float f32x4 __attribute__((ext_vector_type(4)));

// ---------------- fused fp32 -> bf16 conversion of all 5 tensors ----------------
// segments (vec4 counts): x 1048576 | wq 262144 | wk 65536 | wv 65536 | wo 262144
__global__ __launch_bounds__(256) void f2bf_all(const float* __restrict__ x,
                                                const float* __restrict__ wq,
                                                const float* __restrict__ wk,
                                                const float* __restrict__ wv,
                                                const float* __restrict__ wo,
                                                bf16_t* __restrict__ xb,
                                                bf16_t* __restrict__ wqkvb,
                                                bf16_t* __restrict__ wob) {
  int i = blockIdx.x * blockDim.x + threadIdx.x;
  const float* src;
  bf16_t* dst;
  int off;
  if (i < 1048576) { src = x; dst = xb; off = i; }
  else if (i < 1310720) { src = wq; dst = wqkvb; off = i - 1048576; }
  else if (i < 1376256) { src = wk; dst = wqkvb + (size_t)1024 * DIM; off = i - 1310720; }
  else if (i < 1441792) { src = wv; dst = wqkvb + (size_t)1280 * DIM; off = i - 1376256; }
  else { src = wo; dst = wob; off = i - 1441792; }
  float4 f = ((const float4*)src)[off];
  bf16x4 o = {(bf16_t)f.x, (bf16_t)f.y, (bf16_t)f.z, (bf16_t)f.w};
  ((bf16x4*)dst)[off] = o;
}

// ---------------- QKV GEMM with fused per-head RMSNorm epilogue ----------------
// C[M,1536] = A[M,1024] @ B[1536,1024]^T; col groups of 64 = heads:
// heads 0..15 = q (rmsnorm w/ qw), 16..19 = k (rmsnorm w/ kw), 20..23 = v (pass).
__global__ __launch_bounds__(256) void gemm_qkv_rms(const bf16_t* __restrict__ A,
                                                    const bf16_t* __restrict__ B,
                                                    bf16_t* __restrict__ C,
                                                    const float* __restrict__ qw,
                                                    const float* __restrict__ kw,
                                                    int M, int N, int K) {
  __shared__ bf16_t As[128 * 32];
  __shared__ bf16_t Bs[128 * 32];
  const int t = threadIdx.x;
  const int lane = t & 63;
  const int wid = t >> 6;
  const int row0 = blockIdx.y * 128;
  const int col0 = blockIdx.x * 128;
  const int wm = (wid >> 1) * 64;
  const int wn = (wid & 1) * 64;
  const int lquad = lane >> 4;
  const int lcol = lane & 15;

  f32x4 acc[4][4] = {};

  for (int k0 = 0; k0 < K; k0 += 32) {
    const bf16_t* Ag = A + (size_t)row0 * K + k0;
    const bf16_t* Bg = B + (size_t)col0 * K + k0;
#pragma unroll
    for (int i = 0; i < 2; i++) {
      int c = t + i * 256;
      int r = c >> 2, cc = c & 3;
      __builtin_amdgcn_global_load_lds(
          (const __attribute__((address_space(1))) void*)(Ag + (size_t)r * K + cc * 8),
          (__attribute__((address_space(3))) void*)(As + c * 8), 16, 0, 0);
      __builtin_amdgcn_global_load_lds(
          (const __attribute__((address_space(1))) void*)(Bg + (size_t)r * K + cc * 8),
          (__attribute__((address_space(3))) void*)(Bs + c * 8), 16, 0, 0);
    }
    __syncthreads();

    bf16x8 af[4], bfr[4];
#pragma unroll
    for (int mi = 0; mi < 4; mi++)
      af[mi] = *(const bf16x8*)(As + (wm + mi * 16 + lcol) * 32 + lquad * 8);
#pragma unroll
    for (int ni = 0; ni < 4; ni++)
      bfr[ni] = *(const bf16x8*)(Bs + (wn + ni * 16 + lcol) * 32 + lquad * 8);
#pragma unroll
    for (int mi = 0; mi < 4; mi++)
#pragma unroll
      for (int ni = 0; ni < 4; ni++)
        acc[mi][ni] = __builtin_amdgcn_mfma_f32_16x16x32_bf16(af[mi], bfr[ni],
                                                              acc[mi][ni], 0, 0, 0);
    __syncthreads();
  }

  // ---- fused RMSNorm epilogue: wave's 64 cols == one head ----
  const int hcol = (col0 + wn) >> 6;      // 0..23
  const bool isv = (hcol >= 20);
  float wreg[4];
  if (!isv) {
    const float* wp = (hcol < 16) ? qw : kw;
#pragma unroll
    for (int ni = 0; ni < 4; ni++) wreg[ni] = wp[ni * 16 + lcol];
  }

#pragma unroll
  for (int mi = 0; mi < 4; mi++) {
#pragma unroll
    for (int r = 0; r < 4; r++) {
      float norm = 1.0f;
      if (!isv) {
        float ss = 0.0f;
#pragma unroll
        for (int ni = 0; ni < 4; ni++) ss += acc[mi][ni][r] * acc[mi][ni][r];
#pragma unroll
        for (int off = 8; off >= 1; off >>= 1) ss += __shfl_xor(ss, off);
        norm = rsqrtf(ss * (1.0f / 64.0f) + EPS);
      }
      size_t base = (size_t)(row0 + wm + mi * 16 + lquad * 4 + r) * N + col0 + wn + lcol;
#pragma unroll
      for (int ni = 0; ni < 4; ni++) {
        float v = acc[mi][ni][r] * norm;
        if (!isv) v *= wreg[ni];
        C[base + ni * 16] = (bf16_t)v;
      }
    }
  }
}

// ---------------- bf16 MFMA GEMM (m97 structure): C[M,N] = A[M,K] @ B[N,K]^T
template <typename CT>
__global__ __launch_bounds__(256) void gemm_bf16(const bf16_t* __restrict__ A,
                                                 const bf16_t* __restrict__ B,
                                                 CT* __restrict__ C,
                                                 int M, int N, int K) {
  __shared__ bf16_t As[128 * 32];
  __shared__ bf16_t Bs[128 * 32];
  const int t = threadIdx.x;
  const int lane = t & 63;
  const int wid = t >> 6;
  const int row0 = blockIdx.y * 128;
  const int col0 = blockIdx.x * 128;
  const int wm = (wid >> 1) * 64;
  const int wn = (wid & 1) * 64;
  const int lquad = lane >> 4;
  const int lcol = lane & 15;

  f32x4 acc[4][4] = {};

  for (int k0 = 0; k0 < K; k0 += 32) {
    const bf16_t* Ag = A + (size_t)row0 * K + k0;
    const bf16_t* Bg = B + (size_t)col0 * K + k0;
#pragma unroll
    for (int i = 0; i < 2; i++) {
      int c = t + i * 256;
      int r = c >> 2, cc = c & 3;
      __builtin_amdgcn_global_load_lds(
          (const __attribute__((address_space(1))) void*)(Ag + (size_t)r * K + cc * 8),
          (__attribute__((address_space(3))) void*)(As + c * 8), 16, 0, 0);
      __builtin_amdgcn_global_load_lds(
          (const __attribute__((address_space(1))) void*)(Bg + (size_t)r * K + cc * 8),
          (__attribute__((address_space(3))) void*)(Bs + c * 8), 16, 0, 0);
    }
    __syncthreads();

    bf16x8 af[4], bfr[4];
#pragma unroll
    for (int mi = 0; mi < 4; mi++)
      af[mi] = *(const bf16x8*)(As + (wm + mi * 16 + lcol) * 32 + lquad * 8);
#pragma unroll
    for (int ni = 0; ni < 4; ni++)
      bfr[ni] = *(const bf16x8*)(Bs + (wn + ni * 16 + lcol) * 32 + lquad * 8);
#pragma unroll
    for (int mi = 0; mi < 4; mi++)
#pragma unroll
      for (int ni = 0; ni < 4; ni++)
        acc[mi][ni] = __builtin_amdgcn_mfma_f32_16x16x32_bf16(af[mi], bfr[ni],
                                                              acc[mi][ni], 0, 0, 0);
    __syncthreads();
  }

#pragma unroll
  for (int mi = 0; mi < 4; mi++)
#pragma unroll
    for (int ni = 0; ni < 4; ni++) {
      size_t base = (size_t)(row0 + wm + mi * 16 + lquad * 4) * N + col0 + wn + ni * 16 + lcol;
#pragma unroll
      for (int r = 0; r < 4; r++)
        C[base + (size_t)r * N] = (CT)acc[mi][ni][r];
    }
}

// ---------------- MFMA banded ALiBi attention -------------------------------
#define LKP 72  // K row stride in LDS
#define LVP 40  // VT / P row stride

__global__ __launch_bounds__(256) void attn_mfma(const bf16_t* __restrict__ qkv,
                                                 bf16_t* __restrict__ y) {
  __shared__ bf16_t Ks[4][32][LKP];   // [kvh][key][dim]
  __shared__ bf16_t VTs[4][64][LVP];  // [kvh][dim][key]
  __shared__ bf16_t Ps[4][16][LVP];   // [wave][qrow][key]

  const int t = threadIdx.x;
  const int lane = t & 63;
  const int w = t >> 6;
  const int tile = blockIdx.x >> 2;
  const int hgroup = blockIdx.x & 3;
  const int b = tile >> 7;
  const int i0loc = (tile & 127) << 4;
  const int rowbase = b << 11;
  const int rowg0 = rowbase + i0loc;

#pragma unroll
  for (int it = 0; it < 4; it++) {
    int chunk = t + it * 256;
    int kvh = chunk >> 8;
    int key = (chunk >> 3) & 31;
    int dc = chunk & 7;
    int jloc = i0loc - 16 + key;
    int rg = rowbase + (jloc < 0 ? 0 : jloc);
    bf16x8 val = *(const bf16x8*)(qkv + (size_t)rg * 1536 + 1024 + kvh * 64 + dc * 8);
    *(bf16x8*)(&Ks[kvh][key][dc * 8]) = val;
  }
#pragma unroll
  for (int it = 0; it < 32; it++) {
    int idx = t + it * 256;
    int dim = idx & 63;
    int key = (idx >> 6) & 31;
    int kvh = idx >> 11;
    int jloc = i0loc - 16 + key;
    int rg = rowbase + (jloc < 0 ? 0 : jloc);
    VTs[kvh][dim][key] = qkv[(size_t)rg * 1536 + 1280 + kvh * 64 + dim];
  }
  __syncthreads();

  const int col = lane & 15;
  const int quad = lane >> 4;
  const int h = hgroup * 4 + w;
  const int kvh = w;
  const float slope = exp2f(-0.5f * (float)(h + 1));

  bf16x8 kf[2][2];
#pragma unroll
  for (int kt = 0; kt < 2; kt++)
#pragma unroll
    for (int kc = 0; kc < 2; kc++)
      kf[kt][kc] = *(const bf16x8*)(&Ks[kvh][kt * 16 + col][kc * 32 + quad * 8]);
  bf16x8 vf[4];
#pragma unroll
  for (int nt = 0; nt < 4; nt++)
    vf[nt] = *(const bf16x8*)(&VTs[kvh][nt * 16 + col][quad * 8]);

  const bf16_t* qrow = qkv + (size_t)(rowg0 + col) * 1536 + h * 64;
  bf16x8 qf0 = *(const bf16x8*)(qrow + quad * 8);
  bf16x8 qf1 = *(const bf16x8*)(qrow + 32 + quad * 8);

  f32x4 s0 = {}, s1 = {};
  s0 = __builtin_amdgcn_mfma_f32_16x16x32_bf16(qf0, kf[0][0], s0, 0, 0, 0);
  s0 = __builtin_amdgcn_mfma_f32_16x16x32_bf16(qf1, kf[0][1], s0, 0, 0, 0);
  s1 = __builtin_amdgcn_mfma_f32_16x16x32_bf16(qf0, kf[1][0], s1, 0, 0, 0);
  s1 = __builtin_amdgcn_mfma_f32_16x16x32_bf16(qf1, kf[1][1], s1, 0, 0, 0);

  const bool t0dead = (i0loc == 0);
  float sc0[4], sc1[4];
#pragma unroll
  for (int r = 0; r < 4; r++) {
    int rel0 = col - 16 - (quad * 4 + r);
    int rel1 = rel0 + 16;
    bool m0 = t0dead || (rel0 < -WINDOW);
    bool m1 = (rel1 > 0);
    sc0[r] = m0 ? -INFINITY : s0[r] * 0.125f + slope * (float)rel0;
    sc1[r] = m1 ? -INFINITY : s1[r] * 0.125f + slope * (float)rel1;
  }
  float mx[4], sum[4], p0[4], p1[4];
#pragma unroll
  for (int r = 0; r < 4; r++) mx[r] = fmaxf(sc0[r], sc1[r]);
#pragma unroll
  for (int off = 8; off >= 1; off >>= 1)
#pragma unroll
    for (int r = 0; r < 4; r++) mx[r] = fmaxf(mx[r], __shfl_xor(mx[r], off));
#pragma unroll
  for (int r = 0; r < 4; r++) {
    p0[r] = __expf(sc0[r] - mx[r]);
    p1[r] = __expf(sc1[r] - mx[r]);
    sum[r] = p0[r] + p1[r];
  }
#pragma unroll
  for (int off = 8; off >= 1; off >>= 1)
#pragma unroll
    for (int r = 0; r < 4; r++) sum[r] += __shfl_xor(sum[r], off);

#pragma unroll
  for (int r = 0; r < 4; r++) {
    Ps[w][quad * 4 + r][col] = (bf16_t)p0[r];
    Ps[w][quad * 4 + r][16 + col] = (bf16_t)p1[r];
  }
  __syncthreads();
  bf16x8 pf = *(const bf16x8*)(&Ps[w][col][quad * 8]);

  f32x4 o[4] = {};
#pragma unroll
  for (int nt = 0; nt < 4; nt++)
    o[nt] = __builtin_amdgcn_mfma_f32_16x16x32_bf16(pf, vf[nt], o[nt], 0, 0, 0);

#pragma unroll
  for (int nt = 0; nt < 4; nt++)
#pragma unroll
    for (int r = 0; r < 4; r++)
      y[(size_t)(rowg0 + quad * 4 + r) * 1024 + h * 64 + nt * 16 + col] =
          (bf16_t)(o[nt][r] / sum[r]);
}

extern "C" void kernel_launch(void* const* d_in, const int* in_sizes, int n_in,
                              void* d_out, int out_size, void* d_ws, size_t ws_size,
                              hipStream_t stream) {
  const float* x  = (const float*)d_in[0];
  const float* wq = (const float*)d_in[1];
  const float* wk = (const float*)d_in[2];
  const float* wv = (const float*)d_in[3];
  const float* wo = (const float*)d_in[4];
  const float* qw = (const float*)d_in[5];
  const float* kw = (const float*)d_in[6];
  float* out = (float*)d_out;

  const int M = 4096;  // B*L

  bf16_t* xb    = (bf16_t*)d_ws;
  bf16_t* wqkvb = xb + (size_t)M * DIM;        // [1536, 1024]
  bf16_t* wob   = wqkvb + (size_t)1536 * DIM;  // [1024, 1024]
  bf16_t* qkv   = wob + (size_t)DIM * DIM;     // [4096, 1536]
  bf16_t* yb    = qkv + (size_t)M * 1536;      // [4096, 1024]

  dim3 blk(256);
  f2bf_all<<<1703936 / 256, blk, 0, stream>>>(x, wq, wk, wv, wo, xb, wqkvb, wob);

  // QKV projection + fused per-head RMSNorm
  gemm_qkv_rms<<<dim3(1536 / 128, M / 128), blk, 0, stream>>>(xb, wqkvb, qkv, qw, kw, M, 1536, DIM);

  // MFMA banded attention -> yb [4096,1024] bf16
  attn_mfma<<<1024, blk, 0, stream>>>(qkv, yb);

  // output projection: out[4096,1024] = yb @ wob^T (fp32 out)
  gemm_bf16<float><<<dim3(DIM / 128, M / 128), blk, 0, stream>>>(yb, wob, out, M, DIM, DIM);
}